// Round 8
// baseline (147.866 us; speedup 1.0000x reference)
//
#include <hip/hip_runtime.h>

#define IN_DIM 128
#define OUT_DIM 128

typedef __attribute__((ext_vector_type(8))) short short8v;   // 8 bf16 = 4 VGPRs
typedef __attribute__((ext_vector_type(4))) float float4v;
typedef __attribute__((ext_vector_type(4))) unsigned int uint4v;

__device__ __forceinline__ ushort f2bf(float f) {
    unsigned int u = __builtin_bit_cast(unsigned int, f);
    unsigned int r = (u + 0x7fffu + ((u >> 16) & 1u)) >> 16;   // RNE
    return (ushort)r;
}

__device__ __forceinline__ unsigned int pk2bf(float x, float y) {
#if __has_builtin(__builtin_amdgcn_cvt_pk_bf16_f32)
    typedef __attribute__((ext_vector_type(2))) __bf16 bf2;
    bf2 r = __builtin_amdgcn_cvt_pk_bf16_f32(x, y);
    return __builtin_bit_cast(unsigned int, r);
#else
    return (unsigned int)f2bf(x) | ((unsigned int)f2bf(y) << 16);
#endif
}

// ---------------- Kernel 0: prep (Wt only, 16 blocks) ----------------
// Wt[n][k] = bf16(W[k][n]), row stride 136. Coalesced fp32 reads, b32 stores.
__global__ __launch_bounds__(256) void prep_kernel(const float* __restrict__ W,
                                                   ushort* __restrict__ Wt) {
    int k0 = blockIdx.x * 8;
    int n = threadIdx.x & 127;
    int half = threadIdx.x >> 7;
#pragma unroll
    for (int kp = 0; kp < 2; ++kp) {
        int k = k0 + (half * 2 + kp) * 2;
        float v0 = W[k * 128 + n];          // coalesced across lanes
        float v1 = W[(k + 1) * 128 + n];
        *(unsigned int*)&Wt[n * 136 + k] = pk2bf(v0, v1);
    }
}

// ---------------- Kernel 1: T(biased-uint8, per-row scale) = H @ W, + rp tail ----------------
// Blocks [0, nb_gemm): 64-row x 128-col tile, K=128 unrolled (proven core).
// Epilogue: per-row absmax (shfl_xor 16/32 over quarter-lanes), quantize row
// to BIASED uint8 (q+128) with scale S[row] = rowmax/127 -> fetch-cheap
// scatter gather AND single-instruction v_cvt_f32_ubyte decode.
// Blocks [nb_gemm, ...): row_ptr[n] = lower_bound(edst, n) (overlaps gemm).
__global__ __launch_bounds__(256) void gemm_kernel(const float* __restrict__ H,
                                                   const ushort* __restrict__ Wt_g,
                                                   unsigned char* __restrict__ T8,
                                                   float* __restrict__ S, int M,
                                                   const int* __restrict__ edst,
                                                   int* __restrict__ rp,
                                                   int E, int nb_gemm) {
    __shared__ ushort Ws[128 * 136];   // 34816 B

    const int t = threadIdx.x;

    if (blockIdx.x >= nb_gemm) {       // rp tail blocks (block-uniform branch)
        int n = (blockIdx.x - nb_gemm) * 256 + t;
        if (n <= M) {
            int lo = 0, hi = E;
            while (lo < hi) {
                int mid = (lo + hi) >> 1;
                if (edst[mid] < n) lo = mid + 1; else hi = mid;
            }
            rp[n] = lo;
        }
        return;
    }

    const int row0 = blockIdx.x * 64;

#pragma unroll
    for (int f = t; f < 2176; f += 256)
        ((short8v*)Ws)[f] = ((const short8v*)Wt_g)[f];

    const int w = t >> 6;
    const int l = t & 63;
    const int m16 = l & 15;
    const int kq = (l >> 4) * 8;
    const int gr = row0 + w * 16 + m16;

    float4 h[8];
    if (gr < M) {
#pragma unroll
        for (int ks = 0; ks < 4; ++ks) {
            h[ks * 2]     = *(const float4*)&H[gr * 128 + ks * 32 + kq];
            h[ks * 2 + 1] = *(const float4*)&H[gr * 128 + ks * 32 + kq + 4];
        }
    } else {
#pragma unroll
        for (int i = 0; i < 8; ++i) h[i] = make_float4(0.f, 0.f, 0.f, 0.f);
    }

    short8v bfrag[4];
#pragma unroll
    for (int ks = 0; ks < 4; ++ks) {
        uint4v u;
        u[0] = pk2bf(h[ks * 2].x, h[ks * 2].y);
        u[1] = pk2bf(h[ks * 2].z, h[ks * 2].w);
        u[2] = pk2bf(h[ks * 2 + 1].x, h[ks * 2 + 1].y);
        u[3] = pk2bf(h[ks * 2 + 1].z, h[ks * 2 + 1].w);
        bfrag[ks] = __builtin_bit_cast(short8v, u);
    }

    __syncthreads();   // Ws ready

    float4v acc[8];
#pragma unroll
    for (int nt = 0; nt < 8; ++nt) acc[nt] = (float4v){0.f, 0.f, 0.f, 0.f};

#pragma unroll
    for (int ks = 0; ks < 4; ++ks) {
#pragma unroll
        for (int nt = 0; nt < 8; ++nt) {
            short8v afrag = *(const short8v*)&Ws[(nt * 16 + m16) * 136 + ks * 32 + kq];
            acc[nt] = __builtin_amdgcn_mfma_f32_16x16x32_bf16(afrag, bfrag[ks], acc[nt], 0, 0, 0);
        }
    }

    // Per-row absmax across this lane's 32 cols, then across the 4 quarter-
    // lanes sharing row gr (l, l^16, l^32, l^48).
    float mx = 0.f;
#pragma unroll
    for (int nt = 0; nt < 8; ++nt) {
#pragma unroll
        for (int k = 0; k < 4; ++k) mx = fmaxf(mx, fabsf(acc[nt][k]));
    }
    mx = fmaxf(mx, __shfl_xor(mx, 16));
    mx = fmaxf(mx, __shfl_xor(mx, 32));

    const float inv = 127.0f / fmaxf(mx, 1e-20f);

    if (gr < M) {
        const int qd = l >> 4;
        if (qd == 0) S[gr] = mx * (1.0f / 127.0f);
#pragma unroll
        for (int nt = 0; nt < 8; ++nt) {
            unsigned int p = 0;
#pragma unroll
            for (int k = 0; k < 4; ++k) {
                int qi = (int)__builtin_rintf(acc[nt][k] * inv);
                qi = qi > 127 ? 127 : (qi < -127 ? -127 : qi);
                p |= ((unsigned int)(qi + 128) & 0xffu) << (k * 8);   // biased
            }
            *(unsigned int*)&T8[gr * 128 + nt * 16 + qd * 4] = p;
        }
    }
}

// ---------------- Kernel 2: out[n][:] = b + sum_{e} w_e*S[src]*(T8[src][:]-128) ----------------
// COLUMN-SPLIT + XCD AFFINITY: each block handles a 64-col HALF of 4 nodes.
// Dispatch round-robins blockIdx over the 8 XCDs, so blocks with (blk&7)<4
// (-> XCDs 0-3) only gather T8 cols [0,64) -- a 3.2 MB slice that stays
// RESIDENT in each 4-MiB XCD L2. Gathers become L2 hits instead of
// LLC round trips. (Affinity is a perf heuristic only; correctness is
// mapping-independent.)
// Within a wave: EDGE-QUAD structure (R6-proven runtime loop, no conditional
// pipelining -- R7's guarded static batches forced conservative vmcnt(0)).
// Lane owns 4 cols (dword); four 16-lane groups each cover a full 64-B
// half-row = 1 cache line -> one VMEM retires 4 edges. Metadata select: 8
// shfl per 16-edge batch. Pad edges carry ws=0. Cross-quarter combine:
// shfl_xor 16/32; quarter 0 stores float4.
__global__ __launch_bounds__(256) void scatter_kernel(const unsigned char* __restrict__ T8,
                                                      const float* __restrict__ S,
                                                      const int* __restrict__ esrc,
                                                      const float* __restrict__ ew,
                                                      const int* __restrict__ rp,
                                                      const float* __restrict__ b,
                                                      float* __restrict__ out,
                                                      int M, int ngroups) {
    const int blk = blockIdx.x;
    const int halfsel = (blk & 7) >> 2;            // 0: cols 0-63, 1: cols 64-127
    const int i = ((blk >> 3) << 2) + (blk & 3);   // node-group within half
    if (i >= ngroups) return;
    const int node = i * 4 + (threadIdx.x >> 6);
    if (node >= M) return;

    const int lane = threadIdx.x & 63;
    const int quarter = lane >> 4;                 // which edge of each quad
    const unsigned int colb = (unsigned int)halfsel * 64u + (lane & 15u) * 4u;

    const int s = __builtin_amdgcn_readfirstlane(rp[node]);
    const int e = __builtin_amdgcn_readfirstlane(rp[node + 1]);

    float a0 = 0.f, a1 = 0.f, a2 = 0.f, a3 = 0.f;
    float B = 0.f;              // sum of ws over this lane's edges

    for (int c = s; c < e; c += 64) {
        const int idx = c + lane;
        int srcl = 0;
        float wl = 0.f;
        if (idx < e) { srcl = esrc[idx]; wl = ew[idx]; }   // coalesced; pad w=0
        const float wsl = wl * S[srcl];                    // vector-pipe gather
        int nn = e - c;
        if (nn > 64) nn = 64;

        for (int j = 0; j < nn; j += 16) {   // 16 edges per batch (4/quad-group)
            int sq[4];
            float ws[4];
            unsigned int vv[4];
#pragma unroll
            for (int p = 0; p < 4; ++p) {
                const int sl = j + p * 4 + quarter;        // my group's edge
                sq[p] = __shfl(srcl, sl);                  // ds_bpermute
                ws[p] = __shfl(wsl, sl);
            }
#pragma unroll
            for (int p = 0; p < 4; ++p)
                vv[p] = *(const unsigned int*)(T8 + ((unsigned int)sq[p] * 128u + colb));
#pragma unroll
            for (int p = 0; p < 4; ++p) {
                const unsigned int v = vv[p];
                const float w = ws[p];
                B  += w;
                a0 = fmaf((float)(v & 0xffu), w, a0);           // v_cvt_f32_ubyte0
                a1 = fmaf((float)((v >> 8) & 0xffu), w, a1);    // v_cvt_f32_ubyte1
                a2 = fmaf((float)((v >> 16) & 0xffu), w, a2);   // v_cvt_f32_ubyte2
                a3 = fmaf((float)(v >> 24), w, a3);             // v_cvt_f32_ubyte3
            }
        }
    }

    // Combine the 4 quarter-groups (lanes l, l^16, l^32, l^48 share cols).
    a0 += __shfl_xor(a0, 16); a0 += __shfl_xor(a0, 32);
    a1 += __shfl_xor(a1, 16); a1 += __shfl_xor(a1, 32);
    a2 += __shfl_xor(a2, 16); a2 += __shfl_xor(a2, 32);
    a3 += __shfl_xor(a3, 16); a3 += __shfl_xor(a3, 32);
    B  += __shfl_xor(B, 16);  B  += __shfl_xor(B, 32);

    if (quarter == 0) {
        const float4 bb = *(const float4*)&b[colb];
        float4 o;
        o.x = fmaf(-128.0f, B, a0) + bb.x;
        o.y = fmaf(-128.0f, B, a1) + bb.y;
        o.z = fmaf(-128.0f, B, a2) + bb.z;
        o.w = fmaf(-128.0f, B, a3) + bb.w;
        *(float4*)&out[node * 128 + colb] = o;
    }
}

extern "C" void kernel_launch(void* const* d_in, const int* in_sizes, int n_in,
                              void* d_out, int out_size, void* d_ws, size_t ws_size,
                              hipStream_t stream) {
    const float* H    = (const float*)d_in[0];
    const int*   esrc = (const int*)d_in[1];
    const int*   edst = (const int*)d_in[2];
    const float* ew   = (const float*)d_in[3];
    const float* W    = (const float*)d_in[4];
    const float* b    = (const float*)d_in[5];
    float* out = (float*)d_out;

    const int M = in_sizes[0] / IN_DIM;   // 50000 nodes
    const int E = in_sizes[1];            // 1,600,000 edges

    // Workspace layout (~6.8 MB)
    unsigned char* T8 = (unsigned char*)d_ws;                       // M*128 B (biased uint8)
    size_t off = (size_t)M * 128;
    float* S  = (float*)((char*)d_ws + off);                        // M floats
    off += (size_t)M * 4;
    ushort* Wt = (ushort*)((char*)d_ws + off);                      // 128*136*2 B
    off += 128 * 136 * 2;
    int* rp = (int*)((char*)d_ws + off);                            // (M+1) ints

    // Wt transpose (16 blocks)
    prep_kernel<<<16, 256, 0, stream>>>(W, Wt);

    // gemm (biased-uint8 output + per-row scale) + rp tail blocks
    const int nb_gemm = (M + 63) / 64;         // 782
    const int nb_rp   = (M + 1 + 255) / 256;   // 196
    gemm_kernel<<<nb_gemm + nb_rp, 256, 0, stream>>>(H, Wt, T8, S, M, edst, rp, E, nb_gemm);

    // scatter: 2 column-halves x node-groups of 4; mapping needs ngroups4 % 4 == 0
    const int ngroups  = (M + 3) / 4;                // 12500
    const int ngroups4 = ((ngroups + 3) / 4) * 4;    // 12500 (already /4)
    const int nblk     = 2 * ngroups4;               // 25000, divisible by 8
    scatter_kernel<<<nblk, 256, 0, stream>>>(T8, S, esrc, ew, rp, b, out, M, ngroups);
}

// Round 9
// 134.699 us; speedup vs baseline: 1.0977x; 1.0977x over previous
//
#include <hip/hip_runtime.h>

#define IN_DIM 128
#define OUT_DIM 128

typedef __attribute__((ext_vector_type(8))) short short8v;   // 8 bf16 = 4 VGPRs
typedef __attribute__((ext_vector_type(4))) float float4v;
typedef __attribute__((ext_vector_type(4))) unsigned int uint4v;

__device__ __forceinline__ ushort f2bf(float f) {
    unsigned int u = __builtin_bit_cast(unsigned int, f);
    unsigned int r = (u + 0x7fffu + ((u >> 16) & 1u)) >> 16;   // RNE
    return (ushort)r;
}

__device__ __forceinline__ unsigned int pk2bf(float x, float y) {
#if __has_builtin(__builtin_amdgcn_cvt_pk_bf16_f32)
    typedef __attribute__((ext_vector_type(2))) __bf16 bf2;
    bf2 r = __builtin_amdgcn_cvt_pk_bf16_f32(x, y);
    return __builtin_bit_cast(unsigned int, r);
#else
    return (unsigned int)f2bf(x) | ((unsigned int)f2bf(y) << 16);
#endif
}

// ---------------- Kernel 0: prep (Wt only, 16 blocks) ----------------
// Wt[n][k] = bf16(W[k][n]), row stride 136. Coalesced fp32 reads, b32 stores.
__global__ __launch_bounds__(256) void prep_kernel(const float* __restrict__ W,
                                                   ushort* __restrict__ Wt) {
    int k0 = blockIdx.x * 8;
    int n = threadIdx.x & 127;
    int half = threadIdx.x >> 7;
#pragma unroll
    for (int kp = 0; kp < 2; ++kp) {
        int k = k0 + (half * 2 + kp) * 2;
        float v0 = W[k * 128 + n];          // coalesced across lanes
        float v1 = W[(k + 1) * 128 + n];
        *(unsigned int*)&Wt[n * 136 + k] = pk2bf(v0, v1);
    }
}

// ---------------- Kernel 1: T(biased-uint8, per-row scale) = H @ W, + rp tail ----------------
// Blocks [0, nb_gemm): 64-row x 128-col tile, K=128 unrolled (proven core).
// Epilogue: per-row absmax (shfl_xor 16/32 over quarter-lanes), quantize row
// to BIASED uint8 (q+128) with scale S[row] = rowmax/127 -> fetch-cheap
// scatter gather AND single-instruction v_cvt_f32_ubyte decode.
// Blocks [nb_gemm, ...): row_ptr[n] = lower_bound(edst, n) (overlaps gemm).
__global__ __launch_bounds__(256) void gemm_kernel(const float* __restrict__ H,
                                                   const ushort* __restrict__ Wt_g,
                                                   unsigned char* __restrict__ T8,
                                                   float* __restrict__ S, int M,
                                                   const int* __restrict__ edst,
                                                   int* __restrict__ rp,
                                                   int E, int nb_gemm) {
    __shared__ ushort Ws[128 * 136];   // 34816 B

    const int t = threadIdx.x;

    if (blockIdx.x >= nb_gemm) {       // rp tail blocks (block-uniform branch)
        int n = (blockIdx.x - nb_gemm) * 256 + t;
        if (n <= M) {
            int lo = 0, hi = E;
            while (lo < hi) {
                int mid = (lo + hi) >> 1;
                if (edst[mid] < n) lo = mid + 1; else hi = mid;
            }
            rp[n] = lo;
        }
        return;
    }

    const int row0 = blockIdx.x * 64;

#pragma unroll
    for (int f = t; f < 2176; f += 256)
        ((short8v*)Ws)[f] = ((const short8v*)Wt_g)[f];

    const int w = t >> 6;
    const int l = t & 63;
    const int m16 = l & 15;
    const int kq = (l >> 4) * 8;
    const int gr = row0 + w * 16 + m16;

    float4 h[8];
    if (gr < M) {
#pragma unroll
        for (int ks = 0; ks < 4; ++ks) {
            h[ks * 2]     = *(const float4*)&H[gr * 128 + ks * 32 + kq];
            h[ks * 2 + 1] = *(const float4*)&H[gr * 128 + ks * 32 + kq + 4];
        }
    } else {
#pragma unroll
        for (int i = 0; i < 8; ++i) h[i] = make_float4(0.f, 0.f, 0.f, 0.f);
    }

    short8v bfrag[4];
#pragma unroll
    for (int ks = 0; ks < 4; ++ks) {
        uint4v u;
        u[0] = pk2bf(h[ks * 2].x, h[ks * 2].y);
        u[1] = pk2bf(h[ks * 2].z, h[ks * 2].w);
        u[2] = pk2bf(h[ks * 2 + 1].x, h[ks * 2 + 1].y);
        u[3] = pk2bf(h[ks * 2 + 1].z, h[ks * 2 + 1].w);
        bfrag[ks] = __builtin_bit_cast(short8v, u);
    }

    __syncthreads();   // Ws ready

    float4v acc[8];
#pragma unroll
    for (int nt = 0; nt < 8; ++nt) acc[nt] = (float4v){0.f, 0.f, 0.f, 0.f};

#pragma unroll
    for (int ks = 0; ks < 4; ++ks) {
#pragma unroll
        for (int nt = 0; nt < 8; ++nt) {
            short8v afrag = *(const short8v*)&Ws[(nt * 16 + m16) * 136 + ks * 32 + kq];
            acc[nt] = __builtin_amdgcn_mfma_f32_16x16x32_bf16(afrag, bfrag[ks], acc[nt], 0, 0, 0);
        }
    }

    // Per-row absmax across this lane's 32 cols, then across the 4 quarter-
    // lanes sharing row gr (l, l^16, l^32, l^48).
    float mx = 0.f;
#pragma unroll
    for (int nt = 0; nt < 8; ++nt) {
#pragma unroll
        for (int k = 0; k < 4; ++k) mx = fmaxf(mx, fabsf(acc[nt][k]));
    }
    mx = fmaxf(mx, __shfl_xor(mx, 16));
    mx = fmaxf(mx, __shfl_xor(mx, 32));

    const float inv = 127.0f / fmaxf(mx, 1e-20f);

    if (gr < M) {
        const int qd = l >> 4;
        if (qd == 0) S[gr] = mx * (1.0f / 127.0f);
#pragma unroll
        for (int nt = 0; nt < 8; ++nt) {
            unsigned int p = 0;
#pragma unroll
            for (int k = 0; k < 4; ++k) {
                int qi = (int)__builtin_rintf(acc[nt][k] * inv);
                qi = qi > 127 ? 127 : (qi < -127 ? -127 : qi);
                p |= ((unsigned int)(qi + 128) & 0xffu) << (k * 8);   // biased
            }
            *(unsigned int*)&T8[gr * 128 + nt * 16 + qd * 4] = p;
        }
    }
}

// ---------------- Kernel 2: out[n][:] = b + sum_{e} w_e*S[src]*(T8[src][:]-128) ----------------
// TWO NODES PER WAVE (R6-proven pair structure, duplicated state): each wave
// owns consecutive nodes n0,n1 -> two INDEPENDENT dependency chains
// (metadata load -> S gather -> shfl -> T8 gather -> decode) whose loads
// interleave, doubling memory-level parallelism; rp boundary load shared.
// Within a node: lane owns 4 cols (dword); lanes 0-31 read the EVEN edge's
// full 128-B row (= 1 cache line), lanes 32-63 the ODD edge's -> one VMEM
// retires 2 edges. Metadata select per pair: 2 __shfl (ds_bpermute).
// Runtime inner loop, self-contained batches (no conditional issue/decode
// separation -- R7's guarded static batches forced conservative vmcnt(0)).
// Pad edges carry ws=0. Cross-half combine: shfl_xor(32); half 0 stores.
#define PAIR_LOOP(NN, SRCL, WSL, A0, A1, A2, A3, BB)                           \
    for (int j = 0; j < (NN); j += 8) {                                        \
        int sq[4]; float ws[4]; unsigned int vv[4];                            \
        _Pragma("unroll")                                                      \
        for (int p = 0; p < 4; ++p) {                                          \
            const int sl = j + p * 2 + half;                                   \
            sq[p] = __shfl(SRCL, sl);                                          \
            ws[p] = __shfl(WSL, sl);                                           \
        }                                                                      \
        _Pragma("unroll")                                                      \
        for (int p = 0; p < 4; ++p)                                            \
            vv[p] = *(const unsigned int*)(T8 + ((unsigned int)sq[p] * 128u + colb)); \
        _Pragma("unroll")                                                      \
        for (int p = 0; p < 4; ++p) {                                          \
            const unsigned int v = vv[p];                                      \
            const float w = ws[p];                                             \
            BB += w;                                                           \
            A0 = fmaf((float)(v & 0xffu), w, A0);                              \
            A1 = fmaf((float)((v >> 8) & 0xffu), w, A1);                       \
            A2 = fmaf((float)((v >> 16) & 0xffu), w, A2);                      \
            A3 = fmaf((float)(v >> 24), w, A3);                                \
        }                                                                      \
    }

__global__ __launch_bounds__(256) void scatter_kernel(const unsigned char* __restrict__ T8,
                                                      const float* __restrict__ S,
                                                      const int* __restrict__ esrc,
                                                      const float* __restrict__ ew,
                                                      const int* __restrict__ rp,
                                                      const float* __restrict__ b,
                                                      float* __restrict__ out,
                                                      int M) {
    const int wid = threadIdx.x >> 6;
    const int n0 = blockIdx.x * 8 + wid * 2;
    if (n0 >= M) return;
    const int n1 = n0 + 1;
    const int lane = threadIdx.x & 63;
    const int half = lane >> 5;                       // 0: even edges, 1: odd
    const unsigned int colb = (lane & 31u) * 4u;      // byte (=col) offset

    const int s0 = __builtin_amdgcn_readfirstlane(rp[n0]);
    const int e0 = __builtin_amdgcn_readfirstlane(rp[n0 + 1]);   // = s1
    const int e1 = (n1 < M) ? __builtin_amdgcn_readfirstlane(rp[n1 + 1]) : e0;

    float a00 = 0.f, a01 = 0.f, a02 = 0.f, a03 = 0.f, B0 = 0.f;
    float a10 = 0.f, a11 = 0.f, a12 = 0.f, a13 = 0.f, B1 = 0.f;

    int c0 = s0, c1 = e0;
    while (c0 < e0 || c1 < e1) {
        // Metadata for both nodes' current chunks issued back-to-back:
        // two independent chains in flight.
        int src0 = 0; float w0 = 0.f;
        if (c0 < e0) {
            const int idx = c0 + lane;
            if (idx < e0) { src0 = esrc[idx]; w0 = ew[idx]; }
        }
        int src1 = 0; float w1 = 0.f;
        if (c1 < e1) {
            const int idx = c1 + lane;
            if (idx < e1) { src1 = esrc[idx]; w1 = ew[idx]; }
        }
        const float ws0 = w0 * S[src0];   // vector-pipe gathers (L2-resident)
        const float ws1 = w1 * S[src1];

        int nn0 = e0 - c0; if (nn0 < 0) nn0 = 0; if (nn0 > 64) nn0 = 64;
        int nn1 = e1 - c1; if (nn1 < 0) nn1 = 0; if (nn1 > 64) nn1 = 64;

        PAIR_LOOP(nn0, src0, ws0, a00, a01, a02, a03, B0);
        PAIR_LOOP(nn1, src1, ws1, a10, a11, a12, a13, B1);

        c0 += 64; c1 += 64;
    }

    // Combine even-edge half with odd-edge half for both nodes.
    a00 += __shfl_xor(a00, 32); a01 += __shfl_xor(a01, 32);
    a02 += __shfl_xor(a02, 32); a03 += __shfl_xor(a03, 32);
    B0  += __shfl_xor(B0, 32);
    a10 += __shfl_xor(a10, 32); a11 += __shfl_xor(a11, 32);
    a12 += __shfl_xor(a12, 32); a13 += __shfl_xor(a13, 32);
    B1  += __shfl_xor(B1, 32);

    if (half == 0) {
        const float4 bb = *(const float4*)&b[colb];
        float4 o0;
        o0.x = fmaf(-128.0f, B0, a00) + bb.x;
        o0.y = fmaf(-128.0f, B0, a01) + bb.y;
        o0.z = fmaf(-128.0f, B0, a02) + bb.z;
        o0.w = fmaf(-128.0f, B0, a03) + bb.w;
        *(float4*)&out[n0 * 128 + colb] = o0;
        if (n1 < M) {
            float4 o1;
            o1.x = fmaf(-128.0f, B1, a10) + bb.x;
            o1.y = fmaf(-128.0f, B1, a11) + bb.y;
            o1.z = fmaf(-128.0f, B1, a12) + bb.z;
            o1.w = fmaf(-128.0f, B1, a13) + bb.w;
            *(float4*)&out[n1 * 128 + colb] = o1;
        }
    }
}

extern "C" void kernel_launch(void* const* d_in, const int* in_sizes, int n_in,
                              void* d_out, int out_size, void* d_ws, size_t ws_size,
                              hipStream_t stream) {
    const float* H    = (const float*)d_in[0];
    const int*   esrc = (const int*)d_in[1];
    const int*   edst = (const int*)d_in[2];
    const float* ew   = (const float*)d_in[3];
    const float* W    = (const float*)d_in[4];
    const float* b    = (const float*)d_in[5];
    float* out = (float*)d_out;

    const int M = in_sizes[0] / IN_DIM;   // 50000 nodes
    const int E = in_sizes[1];            // 1,600,000 edges

    // Workspace layout (~6.8 MB)
    unsigned char* T8 = (unsigned char*)d_ws;                       // M*128 B (biased uint8)
    size_t off = (size_t)M * 128;
    float* S  = (float*)((char*)d_ws + off);                        // M floats
    off += (size_t)M * 4;
    ushort* Wt = (ushort*)((char*)d_ws + off);                      // 128*136*2 B
    off += 128 * 136 * 2;
    int* rp = (int*)((char*)d_ws + off);                            // (M+1) ints

    // Wt transpose (16 blocks)
    prep_kernel<<<16, 256, 0, stream>>>(W, Wt);

    // gemm (biased-uint8 output + per-row scale) + rp tail blocks
    const int nb_gemm = (M + 63) / 64;         // 782
    const int nb_rp   = (M + 1 + 255) / 256;   // 196
    gemm_kernel<<<nb_gemm + nb_rp, 256, 0, stream>>>(H, Wt, T8, S, M, edst, rp, E, nb_gemm);

    // scatter: 8 nodes per block (4 waves x 2 nodes)
    scatter_kernel<<<(M + 7) / 8, 256, 0, stream>>>(T8, S, esrc, ew, rp, b, out, M);
}